// Round 4
// baseline (119.033 us; speedup 1.0000x reference)
//
#include <hip/hip_runtime.h>
#include <math.h>

// Problem constants (from reference)
#define B_ 4
#define S_ 4096
#define D_ 128
#define N_ 16
#define CHUNK_ 64
#define NCHUNK_ (S_ / CHUNK_)   // 64
#define NCHAN_ (B_ * D_ * N_)   // 8192
#define KC_ 32                  // k2 chunk length
#define KNC_ (S_ / KC_)         // 128 chunks
#define NG_ (CHUNK_ / 4)        // float4 groups per chunk = 16

#define E70F  2.5154386709191672e+30f   // exp(70)
#define EM70F 3.9754497359086468e-31f   // exp(-70)
#define CAPF  3.0e38f
#define LOG2E 1.4426950408889634f

__device__ __forceinline__ float fast_sp(float z) {
    // softplus = max(z,0) + log1p(exp(-|z|)), fast HW transcendentals
    return fmaxf(z, 0.0f) + __logf(1.0f + __expf(-fabsf(z)));
}

__device__ __forceinline__ float exp2_hw(float x) {
#if __has_builtin(__builtin_amdgcn_exp2f)
    return __builtin_amdgcn_exp2f(x);
#else
    return exp2f(x);
#endif
}

template<int CTRL>
__device__ __forceinline__ float dpp_radd(float v) {
    int o = __builtin_amdgcn_mov_dpp(__float_as_int(v), CTRL, 0xf, 0xf, true);
    return v + __int_as_float(o);
}

// ---------------------------------------------------------------------------
// K1: projections + layout transposes.
// ---------------------------------------------------------------------------
__global__ __launch_bounds__(256) void k1_proj(
    const float* __restrict__ x,
    const float* __restrict__ W_B, const float* __restrict__ b_B,
    const float* __restrict__ W_C, const float* __restrict__ b_C,
    const float* __restrict__ W_D, const float* __restrict__ b_D,
    float* __restrict__ xWD, float* __restrict__ BmT, float* __restrict__ CmT,
    float* __restrict__ xT)
{
    __shared__ float xs[16][129];
    const int row0 = blockIdx.x * 16;
    const int b  = row0 >> 12;          // S_=4096 rows per batch
    const int t0 = row0 & (S_ - 1);
    const int tid = threadIdx.x;

    #pragma unroll
    for (int i = 0; i < 8; ++i) {
        int idx = i * 256 + tid;
        xs[idx >> 7][idx & 127] = x[(size_t)row0 * D_ + idx];
    }
    __syncthreads();

    const int r = tid >> 4;
    const int n = tid & 15;
    float a = 0.f, c = 0.f;
    #pragma unroll 4
    for (int k = 0; k < D_; ++k) {
        float xv = xs[r][k];
        a = fmaf(xv, W_B[k * N_ + n], a);
        c = fmaf(xv, W_C[k * N_ + n], c);
    }
    BmT[(size_t)(b * N_ + n) * S_ + t0 + r] = a + b_B[n];
    CmT[(size_t)(b * N_ + n) * S_ + t0 + r] = c + b_C[n];

    if (tid < 16) {
        float dsum = 0.f;
        #pragma unroll 4
        for (int k = 0; k < D_; ++k) dsum = fmaf(xs[tid][k], W_D[k], dsum);
        xWD[row0 + tid] = dsum + b_D[0];
    }

    // x transpose: xT[b,d,t]
    const int tl = tid & 15;
    const int dh = tid >> 4;
    #pragma unroll
    for (int i = 0; i < 8; ++i) {
        int d = i * 16 + dh;
        xT[(size_t)(b * D_ + d) * S_ + t0 + tl] = xs[tl][d];
    }
}

// ---------------------------------------------------------------------------
// K2a: per-(bd,chunk32) sums of softplus(P[d]+xWD[b,t])  -> S2[bd,128]
// ---------------------------------------------------------------------------
__global__ __launch_bounds__(256) void k2a(
    const float* __restrict__ xWD, const float* __restrict__ P,
    float* __restrict__ S2)
{
    int g = blockIdx.x * 256 + threadIdx.x;      // 0..65535
    int ch = g & (KNC_ - 1);
    int bd = g >> 7;
    int bq = bd >> 7;
    int d  = bd & (D_ - 1);
    float Pd = P[d];
    const float* xw = xWD + bq * S_ + ch * KC_;
    float s = 0.f;
    #pragma unroll
    for (int i = 0; i < KC_; ++i) s += fast_sp(Pd + xw[i]);
    S2[g] = s;
}

// ---------------------------------------------------------------------------
// K2b: exclusive wave-scan of the 128 chunk sums per bd -> dstart[bd,128]
// ---------------------------------------------------------------------------
__global__ __launch_bounds__(64) void k2b(
    const float* __restrict__ S2, float* __restrict__ dstart)
{
    const int bd = blockIdx.x;
    const int lane = threadIdx.x;
    float v0 = S2[bd * KNC_ + lane * 2];
    float v1 = S2[bd * KNC_ + lane * 2 + 1];
    float s  = v0 + v1;
    float sc = s;
    #pragma unroll
    for (int off = 1; off < 64; off <<= 1) {
        float o = __shfl_up(sc, off);
        if (lane >= off) sc += o;
    }
    float excl = sc - s;
    dstart[bd * KNC_ + lane * 2]     = excl;
    dstart[bd * KNC_ + lane * 2 + 1] = excl + v0;
}

// ---------------------------------------------------------------------------
// K2c: elementwise disc[bd,t] = softplus(P[d] + xWD[b,t])  (coalesced)
// ---------------------------------------------------------------------------
__global__ __launch_bounds__(256) void k2c(
    const float* __restrict__ xWD, const float* __restrict__ P,
    float* __restrict__ disc)
{
    int e = blockIdx.x * 256 + threadIdx.x;      // 0..2M-1
    int t  = e & (S_ - 1);
    int bd = e >> 12;
    int bq = bd >> 7;
    int d  = bd & (D_ - 1);
    disc[e] = fast_sp(P[d] + xWD[bq * S_ + t]);
}

// ---------------------------------------------------------------------------
// K3: chunked scan over AinvsB, log2-domain, channel-major streams,
//     DEPTH-1 SOFTWARE-PIPELINED float4 loads (the compiler won't do it).
// ---------------------------------------------------------------------------
template <int PHASE_C>
__global__ __launch_bounds__(256, 8) void k3_scan(
    const float* __restrict__ xT, const float* __restrict__ Araw,
    const float* __restrict__ BmT, const float* __restrict__ CmT,
    const float* __restrict__ disc, const float* __restrict__ dstart,
    float* __restrict__ chunkSum, const float* __restrict__ carry,
    float* __restrict__ y)
{
    const int blk = blockIdx.x;
    const int dg = blk & 7;                 // 8 d-groups
    const int ch = (blk >> 3) & (NCHUNK_ - 1);
    const int b  = blk >> 9;
    const int tid = threadIdx.x;
    const int n  = tid & 15;
    const int dl = tid >> 4;
    const int d  = dg * 16 + dl;
    const int bd = b * D_ + d;
    const int cid = bd * N_ + n;

    const float A  = -fast_sp(Araw[d * N_ + n]);   // strictly negative
    const float rA = 1.0f / A;
    const float A2 = A * LOG2E;                    // negative

    const int t0 = ch * CHUNK_;
    const float4* dp4 = (const float4*)(disc + (size_t)bd * S_ + t0);
    const float4* xp4 = (const float4*)(xT   + (size_t)bd * S_ + t0);
    const float4* bp4 = (const float4*)(BmT  + (size_t)(b * N_ + n) * S_ + t0);
    const float4* Cp4 = (const float4*)(CmT  + (size_t)(b * N_ + n) * S_ + t0);
    float* yp = y + ((size_t)b * S_ + t0) * D_ + d;

    // chunk-start cumulative (exclusive), in log2 units
    float cum2 = A2 * dstart[bd * KNC_ + ch * (CHUNK_ / KC_)];
    float run = 0.f;
    if (PHASE_C) run = carry[(size_t)ch * NCHAN_ + cid];

    // prime the pipeline
    float4 dv = dp4[0], xv = xp4[0], bv = bp4[0], Cv;
    if (PHASE_C) Cv = Cp4[0];

    #pragma unroll 4
    for (int t4 = 0; t4 < NG_; ++t4) {
        float4 dn, xn, bn, Cn;
        if (t4 + 1 < NG_) {                    // prefetch next group
            dn = dp4[t4 + 1];
            xn = xp4[t4 + 1];
            bn = bp4[t4 + 1];
            if (PHASE_C) Cn = Cp4[t4 + 1];
        }

        const float dva[4] = {dv.x, dv.y, dv.z, dv.w};
        const float xva[4] = {xv.x, xv.y, xv.z, xv.w};
        const float bva[4] = {bv.x, bv.y, bv.z, bv.w};
        const float Cva[4] = {Cv.x, Cv.y, Cv.z, Cv.w};

        #pragma unroll
        for (int j = 0; j < 4; ++j) {
            float t1 = dva[j] * A2;
            cum2 += t1;
            float ab  = exp2_hw(t1);                    // A_bar in (0,1]
            float w   = fmaf(ab, xva[j], -xva[j]);      // (ab-1)*x
            float Bx  = (bva[j] * rA) * w;
            float aBx = fabsf(Bx);
            float en  = fminf(exp2_hw(-cum2), CAPF);    // exp(-cum), capped
            float m   = aBx * en;
            run += copysignf(fminf(m, E70F), Bx);
            if (PHASE_C) {
                float ecl = (m > E70F) ? aBx * EM70F
                                       : __builtin_amdgcn_rcpf(en);
                float yv = run * ecl * Cva[j];
                yv = dpp_radd<0x121>(yv);   // row_ror:1
                yv = dpp_radd<0x122>(yv);   // row_ror:2
                yv = dpp_radd<0x124>(yv);   // row_ror:4
                yv = dpp_radd<0x128>(yv);   // row_ror:8
                if (n == 0) yp[(size_t)(t4 * 4 + j) * D_] = yv;
            }
        }
        dv = dn; xv = xn; bv = bn;
        if (PHASE_C) Cv = Cn;
    }
    if (!PHASE_C) chunkSum[(size_t)ch * NCHAN_ + cid] = run;
}

// ---------------------------------------------------------------------------
// K3b: exclusive scan of chunk totals per channel, [ch][cid] layout.
// ---------------------------------------------------------------------------
__global__ __launch_bounds__(256) void k3b_scan_chunks(
    const float* __restrict__ csum, float* __restrict__ carry)
{
    int cid = blockIdx.x * 256 + threadIdx.x;    // 0..8191
    float run = 0.f;
    #pragma unroll
    for (int c = 0; c < NCHUNK_; ++c) {
        carry[(size_t)c * NCHAN_ + cid] = run;
        run += csum[(size_t)c * NCHAN_ + cid];
    }
}

// ---------------------------------------------------------------------------
extern "C" void kernel_launch(void* const* d_in, const int* in_sizes, int n_in,
                              void* d_out, int out_size, void* d_ws, size_t ws_size,
                              hipStream_t stream)
{
    const float* x    = (const float*)d_in[0];
    const float* Araw = (const float*)d_in[1];
    const float* P    = (const float*)d_in[2];
    const float* W_B  = (const float*)d_in[3];
    const float* b_B  = (const float*)d_in[4];
    const float* W_C  = (const float*)d_in[5];
    const float* b_C  = (const float*)d_in[6];
    const float* W_D  = (const float*)d_in[7];
    const float* b_D  = (const float*)d_in[8];
    float* y  = (float*)d_out;
    float* ws = (float*)d_ws;

    // workspace layout (floats) ~ 23.6 MB
    float* xWD    = ws;                                    // 16384
    float* BmT    = xWD  + B_ * S_;                        // 262144
    float* CmT    = BmT  + B_ * S_ * N_;                   // 262144
    float* xT     = CmT  + B_ * S_ * N_;                   // 2097152
    float* disc   = xT   + (size_t)B_ * D_ * S_;           // 2097152
    float* S2     = disc + (size_t)B_ * D_ * S_;           // 65536
    float* dstart = S2   + B_ * D_ * KNC_;                 // 65536
    float* csum   = dstart + B_ * D_ * KNC_;               // 524288
    float* carry  = csum + (size_t)NCHAN_ * NCHUNK_;       // 524288

    hipLaunchKernelGGL(k1_proj, dim3(B_ * S_ / 16), dim3(256), 0, stream,
                       x, W_B, b_B, W_C, b_C, W_D, b_D, xWD, BmT, CmT, xT);
    hipLaunchKernelGGL(k2a, dim3(B_ * D_ * KNC_ / 256), dim3(256), 0, stream,
                       xWD, P, S2);
    hipLaunchKernelGGL(k2b, dim3(B_ * D_), dim3(64), 0, stream,
                       S2, dstart);
    hipLaunchKernelGGL(k2c, dim3((size_t)B_ * D_ * S_ / 256), dim3(256), 0, stream,
                       xWD, P, disc);
    hipLaunchKernelGGL((k3_scan<0>), dim3(B_ * NCHUNK_ * (D_ / 16)), dim3(256), 0, stream,
                       xT, Araw, BmT, CmT, disc, dstart, csum, carry, y);
    hipLaunchKernelGGL(k3b_scan_chunks, dim3(NCHAN_ / 256), dim3(256), 0, stream,
                       csum, carry);
    hipLaunchKernelGGL((k3_scan<1>), dim3(B_ * NCHUNK_ * (D_ / 16)), dim3(256), 0, stream,
                       xT, Araw, BmT, CmT, disc, dstart, csum, carry, y);
}

// Round 5
// 83.058 us; speedup vs baseline: 1.4331x; 1.4331x over previous
//
#include <hip/hip_runtime.h>
#include <math.h>

// Problem constants (from reference)
#define B_ 4
#define S_ 4096
#define D_ 128
#define N_ 16
#define CHUNK_ 64
#define NCHUNK_ (S_ / CHUNK_)   // 64
#define NCHAN_ (B_ * D_ * N_)   // 8192
#define KC_ 32                  // k2 chunk length
#define KNC_ (S_ / KC_)         // 128 chunks

#define E70F  2.5154386709191672e+30f   // exp(70)
#define EM70F 3.9754497359086468e-31f   // exp(-70)
#define CAPF  3.0e38f
#define LOG2E 1.4426950408889634f

__device__ __forceinline__ float fast_sp(float z) {
    // softplus = max(z,0) + log1p(exp(-|z|)), fast HW transcendentals
    return fmaxf(z, 0.0f) + __logf(1.0f + __expf(-fabsf(z)));
}

__device__ __forceinline__ float exp2_hw(float x) {
#if __has_builtin(__builtin_amdgcn_exp2f)
    return __builtin_amdgcn_exp2f(x);
#else
    return exp2f(x);
#endif
}

template<int CTRL>
__device__ __forceinline__ float dpp_radd(float v) {
    int o = __builtin_amdgcn_mov_dpp(__float_as_int(v), CTRL, 0xf, 0xf, true);
    return v + __int_as_float(o);
}

// ---------------------------------------------------------------------------
// K1: projections + layout transposes.
// ---------------------------------------------------------------------------
__global__ __launch_bounds__(256) void k1_proj(
    const float* __restrict__ x,
    const float* __restrict__ W_B, const float* __restrict__ b_B,
    const float* __restrict__ W_C, const float* __restrict__ b_C,
    const float* __restrict__ W_D, const float* __restrict__ b_D,
    float* __restrict__ xWD, float* __restrict__ BmT, float* __restrict__ CmT,
    float* __restrict__ xT)
{
    __shared__ float xs[16][129];
    const int row0 = blockIdx.x * 16;
    const int b  = row0 >> 12;          // S_=4096 rows per batch
    const int t0 = row0 & (S_ - 1);
    const int tid = threadIdx.x;

    #pragma unroll
    for (int i = 0; i < 8; ++i) {
        int idx = i * 256 + tid;
        xs[idx >> 7][idx & 127] = x[(size_t)row0 * D_ + idx];
    }
    __syncthreads();

    const int r = tid >> 4;
    const int n = tid & 15;
    float a = 0.f, c = 0.f;
    #pragma unroll 4
    for (int k = 0; k < D_; ++k) {
        float xv = xs[r][k];
        a = fmaf(xv, W_B[k * N_ + n], a);
        c = fmaf(xv, W_C[k * N_ + n], c);
    }
    BmT[(size_t)(b * N_ + n) * S_ + t0 + r] = a + b_B[n];
    CmT[(size_t)(b * N_ + n) * S_ + t0 + r] = c + b_C[n];

    if (tid < 16) {
        float dsum = 0.f;
        #pragma unroll 4
        for (int k = 0; k < D_; ++k) dsum = fmaf(xs[tid][k], W_D[k], dsum);
        xWD[row0 + tid] = dsum + b_D[0];
    }

    // x transpose: xT[b,d,t]
    const int tl = tid & 15;
    const int dh = tid >> 4;
    #pragma unroll
    for (int i = 0; i < 8; ++i) {
        int d = i * 16 + dh;
        xT[(size_t)(b * D_ + d) * S_ + t0 + tl] = xs[tl][d];
    }
}

// ---------------------------------------------------------------------------
// K2a: per-(bd,chunk32) sums of softplus(P[d]+xWD[b,t])  -> S2[bd,128]
// ---------------------------------------------------------------------------
__global__ __launch_bounds__(256) void k2a(
    const float* __restrict__ xWD, const float* __restrict__ P,
    float* __restrict__ S2)
{
    int g = blockIdx.x * 256 + threadIdx.x;      // 0..65535
    int ch = g & (KNC_ - 1);
    int bd = g >> 7;
    int bq = bd >> 7;
    int d  = bd & (D_ - 1);
    float Pd = P[d];
    const float* xw = xWD + bq * S_ + ch * KC_;
    float s = 0.f;
    #pragma unroll
    for (int i = 0; i < KC_; ++i) s += fast_sp(Pd + xw[i]);
    S2[g] = s;
}

// ---------------------------------------------------------------------------
// K2b: exclusive wave-scan of the 128 chunk sums per bd -> dstart[bd,128]
// ---------------------------------------------------------------------------
__global__ __launch_bounds__(64) void k2b(
    const float* __restrict__ S2, float* __restrict__ dstart)
{
    const int bd = blockIdx.x;
    const int lane = threadIdx.x;
    float v0 = S2[bd * KNC_ + lane * 2];
    float v1 = S2[bd * KNC_ + lane * 2 + 1];
    float s  = v0 + v1;
    float sc = s;
    #pragma unroll
    for (int off = 1; off < 64; off <<= 1) {
        float o = __shfl_up(sc, off);
        if (lane >= off) sc += o;
    }
    float excl = sc - s;
    dstart[bd * KNC_ + lane * 2]     = excl;
    dstart[bd * KNC_ + lane * 2 + 1] = excl + v0;
}

// ---------------------------------------------------------------------------
// K2c: elementwise disc[bd,t] = softplus(P[d] + xWD[b,t])  (coalesced)
// ---------------------------------------------------------------------------
__global__ __launch_bounds__(256) void k2c(
    const float* __restrict__ xWD, const float* __restrict__ P,
    float* __restrict__ disc)
{
    int e = blockIdx.x * 256 + threadIdx.x;      // 0..2M-1
    int t  = e & (S_ - 1);
    int bd = e >> 12;
    int bq = bd >> 7;
    int d  = bd & (D_ - 1);
    disc[e] = fast_sp(P[d] + xWD[bq * S_ + t]);
}

// ---------------------------------------------------------------------------
// K3: LDS-staged chunked scan. Per block: stage disc/x (16 d-rows x 64 t)
// and Bm/Cm (16 n-rows x 64 t) into LDS with XOR(row&7) 16B swizzle, one
// barrier, then compute everything from LDS via ds_read_b128.
// ---------------------------------------------------------------------------
template <int PHASE_C>
__global__ __launch_bounds__(256, 8) void k3_scan(
    const float* __restrict__ xT, const float* __restrict__ Araw,
    const float* __restrict__ BmT, const float* __restrict__ CmT,
    const float* __restrict__ disc, const float* __restrict__ dstart,
    float* __restrict__ chunkSum, const float* __restrict__ carry,
    float* __restrict__ y)
{
    __shared__ __align__(16) float lds[5 * 1024];  // disc|x|bm|cm|y, 4KB each
    float* ld_d = lds;
    float* ld_x = lds + 1024;
    float* ld_b = lds + 2048;
    float* ld_c = lds + 3072;
    float* ld_y = lds + 4096;

    const int blk = blockIdx.x;
    const int dg = blk & 7;                 // 8 d-groups
    const int ch = (blk >> 3) & (NCHUNK_ - 1);
    const int b  = blk >> 9;
    const int tid = threadIdx.x;
    const int lane = tid & 63;
    const int w = tid >> 6;                 // wave id 0..3
    const int n  = tid & 15;
    const int dl = tid >> 4;                // 0..15
    const int d  = dg * 16 + dl;
    const int bd = b * D_ + d;
    const int cid = bd * N_ + n;
    const int t0 = ch * CHUNK_;

    // ---- stage: wave w stages array w (rows of 64 t, 16B-swizzled) ----
    {
        const float* src;
        float* dst;
        size_t rstride;
        if (w == 0)      { src = disc + (size_t)(b * D_ + dg * 16) * S_ + t0; dst = ld_d; rstride = S_; }
        else if (w == 1) { src = xT   + (size_t)(b * D_ + dg * 16) * S_ + t0; dst = ld_x; rstride = S_; }
        else if (w == 2) { src = BmT  + (size_t)(b * N_) * S_ + t0;           dst = ld_b; rstride = S_; }
        else             { src = CmT  + (size_t)(b * N_) * S_ + t0;           dst = ld_c; rstride = S_; }
        if (PHASE_C || w < 3) {
            #pragma unroll
            for (int it = 0; it < 4; ++it) {
                int g = it * 64 + lane;
                int row = g >> 4;
                int t16 = g & 15;
                int tlog = t16 ^ (row & 7);       // swizzle: physical t16 holds logical tlog
                float4 v = *(const float4*)(src + (size_t)row * rstride + tlog * 4);
                *(float4*)&dst[row * 64 + t16 * 4] = v;
            }
        }
    }
    __syncthreads();

    const float A  = -fast_sp(Araw[d * N_ + n]);   // strictly negative
    const float rA = 1.0f / A;
    const float A2 = A * LOG2E;                    // negative

    // chunk-start cumulative (exclusive), in log2 units
    float cum2 = A2 * dstart[bd * KNC_ + ch * (CHUNK_ / KC_)];
    float run = 0.f;
    if (PHASE_C) run = carry[(size_t)ch * NCHAN_ + cid];

    const int sdl = dl & 7, sn = n & 7;
    const int offd_base = dl * 64;
    const int offn_base = n * 64;

    #pragma unroll 2
    for (int t4 = 0; t4 < CHUNK_ / 4; ++t4) {
        const int od = offd_base + ((t4 ^ sdl) << 2);
        const int on = offn_base + ((t4 ^ sn) << 2);
        float4 dv = *(const float4*)&ld_d[od];
        float4 xv = *(const float4*)&ld_x[od];
        float4 bv = *(const float4*)&ld_b[on];
        float4 Cv;
        if (PHASE_C) Cv = *(const float4*)&ld_c[on];

        const float dva[4] = {dv.x, dv.y, dv.z, dv.w};
        const float xva[4] = {xv.x, xv.y, xv.z, xv.w};
        const float bva[4] = {bv.x, bv.y, bv.z, bv.w};
        const float Cva[4] = {Cv.x, Cv.y, Cv.z, Cv.w};

        #pragma unroll
        for (int j = 0; j < 4; ++j) {
            float t1 = dva[j] * A2;
            cum2 += t1;
            float ab  = exp2_hw(t1);                    // A_bar in (0,1]
            float ww  = fmaf(ab, xva[j], -xva[j]);      // (ab-1)*x
            float Bx  = (bva[j] * rA) * ww;
            float aBx = fabsf(Bx);
            float en  = fminf(exp2_hw(-cum2), CAPF);    // exp(-cum), capped
            float m   = aBx * en;
            run += copysignf(fminf(m, E70F), Bx);
            if (PHASE_C) {
                float ecl = (m > E70F) ? aBx * EM70F
                                       : __builtin_amdgcn_rcpf(en);
                float yv = run * ecl * Cva[j];
                yv = dpp_radd<0x121>(yv);   // row_ror:1
                yv = dpp_radd<0x122>(yv);   // row_ror:2
                yv = dpp_radd<0x124>(yv);   // row_ror:4
                yv = dpp_radd<0x128>(yv);   // row_ror:8
                if (n == 0) ld_y[(t4 * 4 + j) * 16 + dl] = yv;
            }
        }
    }

    if (!PHASE_C) {
        chunkSum[(size_t)ch * NCHAN_ + cid] = run;
    } else {
        __syncthreads();
        // vectorized y writeback: 64 t x 16 d tile
        int t  = tid >> 2;
        int dp = tid & 3;
        float4 v = *(const float4*)&ld_y[t * 16 + dp * 4];
        *(float4*)&y[((size_t)b * S_ + t0 + t) * D_ + dg * 16 + dp * 4] = v;
    }
}

// ---------------------------------------------------------------------------
// K3b: exclusive scan of chunk totals per channel, [ch][cid] layout.
// ---------------------------------------------------------------------------
__global__ __launch_bounds__(256) void k3b_scan_chunks(
    const float* __restrict__ csum, float* __restrict__ carry)
{
    int cid = blockIdx.x * 256 + threadIdx.x;    // 0..8191
    float run = 0.f;
    #pragma unroll
    for (int c = 0; c < NCHUNK_; ++c) {
        carry[(size_t)c * NCHAN_ + cid] = run;
        run += csum[(size_t)c * NCHAN_ + cid];
    }
}

// ---------------------------------------------------------------------------
extern "C" void kernel_launch(void* const* d_in, const int* in_sizes, int n_in,
                              void* d_out, int out_size, void* d_ws, size_t ws_size,
                              hipStream_t stream)
{
    const float* x    = (const float*)d_in[0];
    const float* Araw = (const float*)d_in[1];
    const float* P    = (const float*)d_in[2];
    const float* W_B  = (const float*)d_in[3];
    const float* b_B  = (const float*)d_in[4];
    const float* W_C  = (const float*)d_in[5];
    const float* b_C  = (const float*)d_in[6];
    const float* W_D  = (const float*)d_in[7];
    const float* b_D  = (const float*)d_in[8];
    float* y  = (float*)d_out;
    float* ws = (float*)d_ws;

    // workspace layout (floats) ~ 23.6 MB
    float* xWD    = ws;                                    // 16384
    float* BmT    = xWD  + B_ * S_;                        // 262144
    float* CmT    = BmT  + B_ * S_ * N_;                   // 262144
    float* xT     = CmT  + B_ * S_ * N_;                   // 2097152
    float* disc   = xT   + (size_t)B_ * D_ * S_;           // 2097152
    float* S2     = disc + (size_t)B_ * D_ * S_;           // 65536
    float* dstart = S2   + B_ * D_ * KNC_;                 // 65536
    float* csum   = dstart + B_ * D_ * KNC_;               // 524288
    float* carry  = csum + (size_t)NCHAN_ * NCHUNK_;       // 524288

    hipLaunchKernelGGL(k1_proj, dim3(B_ * S_ / 16), dim3(256), 0, stream,
                       x, W_B, b_B, W_C, b_C, W_D, b_D, xWD, BmT, CmT, xT);
    hipLaunchKernelGGL(k2a, dim3(B_ * D_ * KNC_ / 256), dim3(256), 0, stream,
                       xWD, P, S2);
    hipLaunchKernelGGL(k2b, dim3(B_ * D_), dim3(64), 0, stream,
                       S2, dstart);
    hipLaunchKernelGGL(k2c, dim3((size_t)B_ * D_ * S_ / 256), dim3(256), 0, stream,
                       xWD, P, disc);
    hipLaunchKernelGGL((k3_scan<0>), dim3(B_ * NCHUNK_ * (D_ / 16)), dim3(256), 0, stream,
                       xT, Araw, BmT, CmT, disc, dstart, csum, carry, y);
    hipLaunchKernelGGL(k3b_scan_chunks, dim3(NCHAN_ / 256), dim3(256), 0, stream,
                       csum, carry);
    hipLaunchKernelGGL((k3_scan<1>), dim3(B_ * NCHUNK_ * (D_ / 16)), dim3(256), 0, stream,
                       xT, Araw, BmT, CmT, disc, dstart, csum, carry, y);
}

// Round 6
// 73.188 us; speedup vs baseline: 1.6264x; 1.1348x over previous
//
#include <hip/hip_runtime.h>
#include <math.h>

// Problem constants (from reference)
#define B_ 4
#define S_ 4096
#define D_ 128
#define N_ 16
#define CHUNK_ 64
#define NCHUNK_ (S_ / CHUNK_)   // 64
#define NCHAN_ (B_ * D_ * N_)   // 8192
#define KC_ 32                  // k2 chunk length
#define KNC_ (S_ / KC_)         // 128 chunks

#define CAPF  3.0e38f
#define LOG2E 1.4426950408889634f
#define C70F  100.98865286222744f       // 70 * log2(e)

__device__ __forceinline__ float fast_sp(float z) {
    // softplus = max(z,0) + log1p(exp(-|z|)), fast HW transcendentals
    return fmaxf(z, 0.0f) + __logf(1.0f + __expf(-fabsf(z)));
}

__device__ __forceinline__ float exp2_hw(float x) {
#if __has_builtin(__builtin_amdgcn_exp2f)
    return __builtin_amdgcn_exp2f(x);
#else
    return exp2f(x);
#endif
}

template<int CTRL>
__device__ __forceinline__ float dpp_radd(float v) {
    int o = __builtin_amdgcn_mov_dpp(__float_as_int(v), CTRL, 0xf, 0xf, true);
    return v + __int_as_float(o);
}

// ---------------------------------------------------------------------------
// K1: projections. xWD[b,t]; BmT[b,n,t]; CmT[b,n,t] (coalesced via LDS).
// ---------------------------------------------------------------------------
__global__ __launch_bounds__(256) void k1_proj(
    const float* __restrict__ x,
    const float* __restrict__ W_B, const float* __restrict__ b_B,
    const float* __restrict__ W_C, const float* __restrict__ b_C,
    const float* __restrict__ W_D, const float* __restrict__ b_D,
    float* __restrict__ xWD, float* __restrict__ BmT, float* __restrict__ CmT)
{
    __shared__ float xs[16][129];
    __shared__ float sB[16][17], sC[16][17];
    const int row0 = blockIdx.x * 16;
    const int b  = row0 >> 12;          // S_=4096 rows per batch
    const int t0 = row0 & (S_ - 1);
    const int tid = threadIdx.x;

    #pragma unroll
    for (int i = 0; i < 8; ++i) {
        int idx = i * 256 + tid;
        xs[idx >> 7][idx & 127] = x[(size_t)row0 * D_ + idx];
    }
    __syncthreads();

    const int r = tid >> 4;
    const int n = tid & 15;
    float a = 0.f, c = 0.f;
    #pragma unroll 4
    for (int k = 0; k < D_; ++k) {
        float xv = xs[r][k];
        a = fmaf(xv, W_B[k * N_ + n], a);
        c = fmaf(xv, W_C[k * N_ + n], c);
    }
    sB[n][r] = a + b_B[n];
    sC[n][r] = c + b_C[n];

    if (tid < 16) {
        float dsum = 0.f;
        #pragma unroll 4
        for (int k = 0; k < D_; ++k) dsum = fmaf(xs[tid][k], W_D[k], dsum);
        xWD[row0 + tid] = dsum + b_D[0];
    }
    __syncthreads();

    const int n2 = tid >> 4, r2 = tid & 15;
    BmT[(size_t)(b * N_ + n2) * S_ + t0 + r2] = sB[n2][r2];
    CmT[(size_t)(b * N_ + n2) * S_ + t0 + r2] = sC[n2][r2];
}

// ---------------------------------------------------------------------------
// KS: fused per-chunk softplus sums + block-scan -> dstart[bd,128]
//     (exclusive prefix of sum_{t<chunk*32} softplus(P[d]+xWD[b,t]))
// ---------------------------------------------------------------------------
__global__ __launch_bounds__(128) void kS(
    const float* __restrict__ xWD, const float* __restrict__ P,
    float* __restrict__ dstart)
{
    __shared__ float wtot[2];
    const int bd = blockIdx.x;           // 0..511
    const int b = bd >> 7, d = bd & (D_ - 1);
    const int c = threadIdx.x;           // chunk 0..127
    const float Pd = P[d];
    const float* xw = xWD + b * S_ + c * KC_;
    float s = 0.f;
    #pragma unroll
    for (int i = 0; i < KC_; i += 4) {
        float4 v = *(const float4*)(xw + i);
        s += fast_sp(Pd + v.x) + fast_sp(Pd + v.y)
           + fast_sp(Pd + v.z) + fast_sp(Pd + v.w);
    }
    const int lane = c & 63, wv = c >> 6;
    float sc = s;
    #pragma unroll
    for (int off = 1; off < 64; off <<= 1) {
        float o = __shfl_up(sc, off);
        if (lane >= off) sc += o;
    }
    if (lane == 63) wtot[wv] = sc;
    __syncthreads();
    float base = (wv == 1) ? wtot[0] : 0.f;
    dstart[bd * KNC_ + c] = base + sc - s;   // exclusive
}

// ---------------------------------------------------------------------------
// K3: LDS-staged chunked scan, disc computed in-LDS, x transposed in-LDS.
//  Scaled log2-domain: cum2' = A2*dcum + C70; en_s = exp2(-cum2') in
//  [e^-70, CAP]; clamp at m_s>1; ecl_s = clamped ? |Bx| : rcp(en_s).
// ---------------------------------------------------------------------------
template <int PHASE_C>
__global__ __launch_bounds__(256, 8) void k3_scan(
    const float* __restrict__ x, const float* __restrict__ Araw,
    const float* __restrict__ P, const float* __restrict__ xWD,
    const float* __restrict__ BmT, const float* __restrict__ CmT,
    const float* __restrict__ dstart,
    float* __restrict__ chunkSum, const float* __restrict__ carry,
    float* __restrict__ y)
{
    __shared__ __align__(16) float lds[PHASE_C ? 5 * 1024 : 3 * 1024];
    float* ld_x = lds;
    float* ld_b = lds + 1024;
    float* ld_d = lds + 2048;
    float* ld_c = lds + (PHASE_C ? 3072 : 0);
    float* ld_y = lds + (PHASE_C ? 4096 : 0);

    const int blk = blockIdx.x;
    const int dg = blk & 7;                 // 8 d-groups
    const int ch = (blk >> 3) & (NCHUNK_ - 1);
    const int b  = blk >> 9;
    const int tid = threadIdx.x;
    const int lane = tid & 63;
    const int w = tid >> 6;                 // wave id 0..3
    const int n  = tid & 15;
    const int dl = tid >> 4;                // 0..15
    const int d  = dg * 16 + dl;
    const int bd = b * D_ + d;
    const int cid = bd * N_ + n;
    const int t0 = ch * CHUNK_;

    // ---- stage ----
    if (w == 0) {
        // x tile: 64 t x 16 d, transposed into ld_x[d][t] (swizzled)
        const float* src = x + ((size_t)b * S_ + t0) * D_ + dg * 16;
        #pragma unroll
        for (int it = 0; it < 4; ++it) {
            int g = it * 64 + lane;
            int t = g >> 2, dq = g & 3;
            float4 v = *(const float4*)(src + (size_t)t * D_ + dq * 4);
            int t4 = t >> 2, tl = t & 3;
            const float va[4] = {v.x, v.y, v.z, v.w};
            #pragma unroll
            for (int j = 0; j < 4; ++j) {
                int dd = dq * 4 + j;
                ld_x[dd * 64 + ((t4 ^ (dd & 7)) << 2) + tl] = va[j];
            }
        }
    } else if (w == 1) {
        const float* src = BmT + (size_t)(b * N_) * S_ + t0;
        #pragma unroll
        for (int it = 0; it < 4; ++it) {
            int g = it * 64 + lane;
            int row = g >> 4, t16 = g & 15;
            int tlog = t16 ^ (row & 7);
            *(float4*)&ld_b[row * 64 + t16 * 4] =
                *(const float4*)(src + (size_t)row * S_ + tlog * 4);
        }
    } else if (PHASE_C && w == 2) {
        const float* src = CmT + (size_t)(b * N_) * S_ + t0;
        #pragma unroll
        for (int it = 0; it < 4; ++it) {
            int g = it * 64 + lane;
            int row = g >> 4, t16 = g & 15;
            int tlog = t16 ^ (row & 7);
            *(float4*)&ld_c[row * 64 + t16 * 4] =
                *(const float4*)(src + (size_t)row * S_ + tlog * 4);
        }
    } else if (w == (PHASE_C ? 3 : 2)) {
        // disc tile: compute softplus(P[d] + xWD[b,t]) for 16 d x 64 t
        float v = xWD[b * S_ + t0 + lane];
        int t4 = lane >> 2, tl = lane & 3;
        #pragma unroll
        for (int dl2 = 0; dl2 < 16; ++dl2) {
            float sp = fast_sp(P[dg * 16 + dl2] + v);
            ld_d[dl2 * 64 + ((t4 ^ (dl2 & 7)) << 2) + tl] = sp;
        }
    }
    __syncthreads();

    const float A  = -fast_sp(Araw[d * N_ + n]);   // strictly negative
    const float rA = 1.0f / A;
    const float A2 = A * LOG2E;                    // negative

    // chunk-start cumulative (exclusive), shifted by +70*log2e
    float cum2 = fmaf(A2, dstart[bd * KNC_ + ch * (CHUNK_ / KC_)], C70F);
    float run = 0.f;
    if (PHASE_C) run = carry[(size_t)ch * NCHAN_ + cid];

    const int sdl = dl & 7, sn = n & 7;
    const int offd_base = dl * 64;
    const int offn_base = n * 64;

    #pragma unroll 2
    for (int t4 = 0; t4 < CHUNK_ / 4; ++t4) {
        const int od = offd_base + ((t4 ^ sdl) << 2);
        const int on = offn_base + ((t4 ^ sn) << 2);
        float4 dv = *(const float4*)&ld_d[od];
        float4 xv = *(const float4*)&ld_x[od];
        float4 bv = *(const float4*)&ld_b[on];
        float4 Cv;
        if (PHASE_C) Cv = *(const float4*)&ld_c[on];

        const float dva[4] = {dv.x, dv.y, dv.z, dv.w};
        const float xva[4] = {xv.x, xv.y, xv.z, xv.w};
        const float bva[4] = {bv.x, bv.y, bv.z, bv.w};
        const float Cva[4] = {Cv.x, Cv.y, Cv.z, Cv.w};

        #pragma unroll
        for (int j = 0; j < 4; ++j) {
            float t1 = dva[j] * A2;
            cum2 += t1;
            float ab  = exp2_hw(t1);                    // A_bar in (0,1]
            float ww  = fmaf(ab, xva[j], -xva[j]);      // (ab-1)*x
            float Bx  = (bva[j] * rA) * ww;
            float aBx = fabsf(Bx);
            float en  = fminf(exp2_hw(-cum2), CAPF);    // exp(-cum-70), capped
            float m   = aBx * en;
            run += copysignf(fminf(m, 1.0f), Bx);
            if (PHASE_C) {
                float ecl = (m > 1.0f) ? aBx : __builtin_amdgcn_rcpf(en);
                float yv = run * ecl * Cva[j];
                yv = dpp_radd<0x121>(yv);   // row_ror:1
                yv = dpp_radd<0x122>(yv);   // row_ror:2
                yv = dpp_radd<0x124>(yv);   // row_ror:4
                yv = dpp_radd<0x128>(yv);   // row_ror:8
                if (n == 0) ld_y[(t4 * 4 + j) * 16 + dl] = yv;
            }
        }
    }

    if (!PHASE_C) {
        chunkSum[(size_t)ch * NCHAN_ + cid] = run;
    } else {
        __syncthreads();
        // vectorized y writeback: 64 t x 16 d tile
        int t  = tid >> 2;
        int dp = tid & 3;
        float4 v = *(const float4*)&ld_y[t * 16 + dp * 4];
        *(float4*)&y[((size_t)b * S_ + t0 + t) * D_ + dg * 16 + dp * 4] = v;
    }
}

// ---------------------------------------------------------------------------
// K3b: exclusive scan of chunk totals per channel, [ch][cid] layout.
// ---------------------------------------------------------------------------
__global__ __launch_bounds__(256) void k3b_scan_chunks(
    const float* __restrict__ csum, float* __restrict__ carry)
{
    int cid = blockIdx.x * 256 + threadIdx.x;    // 0..8191
    float run = 0.f;
    #pragma unroll
    for (int c = 0; c < NCHUNK_; ++c) {
        carry[(size_t)c * NCHAN_ + cid] = run;
        run += csum[(size_t)c * NCHAN_ + cid];
    }
}

// ---------------------------------------------------------------------------
extern "C" void kernel_launch(void* const* d_in, const int* in_sizes, int n_in,
                              void* d_out, int out_size, void* d_ws, size_t ws_size,
                              hipStream_t stream)
{
    const float* x    = (const float*)d_in[0];
    const float* Araw = (const float*)d_in[1];
    const float* P    = (const float*)d_in[2];
    const float* W_B  = (const float*)d_in[3];
    const float* b_B  = (const float*)d_in[4];
    const float* W_C  = (const float*)d_in[5];
    const float* b_C  = (const float*)d_in[6];
    const float* W_D  = (const float*)d_in[7];
    const float* b_D  = (const float*)d_in[8];
    float* y  = (float*)d_out;
    float* ws = (float*)d_ws;

    // workspace layout (floats) ~ 6.7 MB
    float* xWD    = ws;                                    // 16384
    float* BmT    = xWD  + B_ * S_;                        // 262144
    float* CmT    = BmT  + B_ * S_ * N_;                   // 262144
    float* dstart = CmT  + B_ * S_ * N_;                   // 65536
    float* csum   = dstart + B_ * D_ * KNC_;               // 524288
    float* carry  = csum + (size_t)NCHAN_ * NCHUNK_;       // 524288

    hipLaunchKernelGGL(k1_proj, dim3(B_ * S_ / 16), dim3(256), 0, stream,
                       x, W_B, b_B, W_C, b_C, W_D, b_D, xWD, BmT, CmT);
    hipLaunchKernelGGL(kS, dim3(B_ * D_), dim3(128), 0, stream,
                       xWD, P, dstart);
    hipLaunchKernelGGL((k3_scan<0>), dim3(B_ * NCHUNK_ * (D_ / 16)), dim3(256), 0, stream,
                       x, Araw, P, xWD, BmT, CmT, dstart, csum, carry, y);
    hipLaunchKernelGGL(k3b_scan_chunks, dim3(NCHAN_ / 256), dim3(256), 0, stream,
                       csum, carry);
    hipLaunchKernelGGL((k3_scan<1>), dim3(B_ * NCHUNK_ * (D_ / 16)), dim3(256), 0, stream,
                       x, Araw, P, xWD, BmT, CmT, dstart, csum, carry, y);
}